// Round 6
// baseline (258.219 us; speedup 1.0000x reference)
//
#include <hip/hip_runtime.h>
#include <cstddef>

#define BATCH 32
#define EMBD 1024
#define SCTX 1023   // cached positions
#define CTXF 1024   // full context after concat
#define HIDD 4096
#define VOC 65535

// ---------------- embed: x[b] = emb[idx[b]] + pos[0] ----------------
__global__ void embed_kernel(const int* __restrict__ idx, const float* __restrict__ emb,
                             const float* __restrict__ pos, float* __restrict__ x) {
  int b = blockIdx.x, t = threadIdx.x;  // 32 blocks x 256
  const float4* er = (const float4*)(emb + (size_t)idx[b] * EMBD);
  const float4* pr = (const float4*)pos;
  float4 e = er[t], p = pr[t];
  ((float4*)(x + (size_t)b * EMBD))[t] = make_float4(e.x + p.x, e.y + p.y, e.z + p.z, e.w + p.w);
}

// ---------------- LDS-staged skinny GEMM (X broadcast from LDS) ----------------
template <int CHK>
__global__ __launch_bounds__(256) void skgemm_lds(const float* __restrict__ X,
                                                  const float* __restrict__ W,
                                                  float* __restrict__ Pout, int N, int K) {
  __shared__ float xt[CHK][BATCH];
  int t = threadIdx.x;
  int p = blockIdx.y;
  int i0 = p * CHK;
  for (int m = t; m < CHK * BATCH; m += 256) {
    int i = m >> 5, b = m & 31;
    xt[i][b] = X[b * K + i0 + i];
  }
  __syncthreads();

  int j = blockIdx.x * 256 + t;
  float acc[BATCH];
#pragma unroll
  for (int b = 0; b < BATCH; ++b) acc[b] = 0.f;
  const float* wp = W + (size_t)i0 * N + j;
#pragma unroll 8
  for (int i = 0; i < CHK; ++i) {
    float w = wp[(size_t)i * N];
#pragma unroll
    for (int b = 0; b < BATCH; ++b) acc[b] = fmaf(xt[i][b], w, acc[b]);
  }
#pragma unroll
  for (int b = 0; b < BATCH; ++b) Pout[((size_t)p * BATCH + b) * N + j] = acc[b];
}

// QKV: z selects weight; partial layout [z][p][b][j]
template <int CHK>
__global__ __launch_bounds__(256) void qkv_lds(const float* __restrict__ X,
                                               const float* __restrict__ Wk,
                                               const float* __restrict__ Wv,
                                               const float* __restrict__ Wq,
                                               float* __restrict__ Pout, int nch) {
  __shared__ float xt[CHK][BATCH];
  int t = threadIdx.x;
  int p = blockIdx.y;
  int i0 = p * CHK;
  for (int m = t; m < CHK * BATCH; m += 256) {
    int i = m >> 5, b = m & 31;
    xt[i][b] = X[b * EMBD + i0 + i];
  }
  __syncthreads();

  const float* __restrict__ W = (blockIdx.z == 0) ? Wk : (blockIdx.z == 1) ? Wv : Wq;
  int j = blockIdx.x * 256 + t;
  float acc[BATCH];
#pragma unroll
  for (int b = 0; b < BATCH; ++b) acc[b] = 0.f;
  const float* wp = W + (size_t)i0 * EMBD + j;
#pragma unroll 8
  for (int i = 0; i < CHK; ++i) {
    float w = wp[(size_t)i * EMBD];
#pragma unroll
    for (int b = 0; b < BATCH; ++b) acc[b] = fmaf(xt[i][b], w, acc[b]);
  }
#pragma unroll
  for (int b = 0; b < BATCH; ++b)
    Pout[((size_t)(blockIdx.z * nch + p) * BATCH + b) * EMBD + j] = acc[b];
}

__global__ void reduce_qkv(const float* __restrict__ part, int P,
                           const float* __restrict__ bk, const float* __restrict__ bv,
                           const float* __restrict__ bq,
                           float* __restrict__ kout, float* __restrict__ vout,
                           float* __restrict__ qout) {
  int z = blockIdx.y;
  int m = blockIdx.x * 256 + threadIdx.x;       // < 32768
  float s = 0.f;
  for (int p = 0; p < P; ++p) s += part[(size_t)(z * P + p) * (BATCH * EMBD) + m];
  const float* bias = (z == 0) ? bk : (z == 1) ? bv : bq;
  float* out = (z == 0) ? kout : (z == 1) ? vout : qout;
  out[m] = s + bias[m & (EMBD - 1)];
}

// out[m] = act( sum_p part[p][m] + bias[m & mask] )
__global__ void reduce_ep(const float* __restrict__ part, int P,
                          const float* __restrict__ bias, float* __restrict__ out,
                          int total, int mask, int act) {
  int m = blockIdx.x * 256 + threadIdx.x;
  if (m >= total) return;
  float s = 0.f;
  for (int p = 0; p < P; ++p) s += part[(size_t)p * total + m];
  if (bias) s += bias[m & mask];
  if (act == 1) s = 0.5f * s * (1.f + erff(s * 0.70710678118654752f));
  out[m] = s;
}

// ---------------- attention ----------------
// grid (64, 32): block = 4 waves, each wave computes 4 score rows concurrently
__global__ void scores_kernel(const float* __restrict__ q, const float* __restrict__ kcache,
                              const float* __restrict__ knew, float* __restrict__ scores) {
  int b = blockIdx.y;
  int wave = threadIdx.x >> 6, lane = threadIdx.x & 63;
  const float* qb = q + (size_t)b * EMBD;
  float4 qf[4];
#pragma unroll
  for (int r = 0; r < 4; ++r) qf[r] = *(const float4*)(qb + r * 256 + lane * 4);
  int sbase = blockIdx.x * 16 + wave * 4;
  const float* kr[4];
  float acc[4] = {0.f, 0.f, 0.f, 0.f};
#pragma unroll
  for (int it = 0; it < 4; ++it) {
    int s = sbase + it;
    kr[it] = (s < SCTX) ? (kcache + ((size_t)b * SCTX + s) * EMBD)
                        : (knew + (size_t)b * EMBD);
  }
#pragma unroll
  for (int r = 0; r < 4; ++r) {
#pragma unroll
    for (int it = 0; it < 4; ++it) {
      float4 kf = *(const float4*)(kr[it] + r * 256 + lane * 4);
      acc[it] += qf[r].x * kf.x + qf[r].y * kf.y + qf[r].z * kf.z + qf[r].w * kf.w;
    }
  }
#pragma unroll
  for (int it = 0; it < 4; ++it) {
    float a = acc[it];
#pragma unroll
    for (int m = 32; m > 0; m >>= 1) a += __shfl_xor(a, m, 64);
    if (lane == 0) scores[(size_t)b * CTXF + sbase + it] = a * 0.03125f;  // 1/sqrt(1024)
  }
}

__global__ void softmax_kernel(float* __restrict__ sc) {
  int b = blockIdx.x;
  int t = threadIdx.x;  // 1024
  __shared__ float red[16];
  float v = sc[(size_t)b * CTXF + t];
  float m = v;
#pragma unroll
  for (int d = 32; d > 0; d >>= 1) m = fmaxf(m, __shfl_xor(m, d, 64));
  if ((t & 63) == 0) red[t >> 6] = m;
  __syncthreads();
  float bm = red[0];
#pragma unroll
  for (int w = 1; w < 16; ++w) bm = fmaxf(bm, red[w]);
  float e = expf(v - bm);
  __syncthreads();
  float s = e;
#pragma unroll
  for (int d = 32; d > 0; d >>= 1) s += __shfl_xor(s, d, 64);
  if ((t & 63) == 0) red[t >> 6] = s;
  __syncthreads();
  float bs = 0.f;
#pragma unroll
  for (int w = 0; w < 16; ++w) bs += red[w];
  sc[(size_t)b * CTXF + t] = e / bs;
}

// grid (32, 32): 32 chunks of 32 rows
__global__ void pv_kernel(const float* __restrict__ probs, const float* __restrict__ vcache,
                          const float* __restrict__ vnew, float* __restrict__ part) {
  int b = blockIdx.y;
  int p = blockIdx.x;
  int t = threadIdx.x;  // 256
  float acc[4] = {0.f, 0.f, 0.f, 0.f};
  int s0 = p * 32;
#pragma unroll 4
  for (int s = s0; s < s0 + 32; ++s) {
    float pr = probs[(size_t)b * CTXF + s];
    const float* vrow = (s < SCTX) ? (vcache + ((size_t)b * SCTX + s) * EMBD)
                                   : (vnew + (size_t)b * EMBD);
#pragma unroll
    for (int r = 0; r < 4; ++r) acc[r] = fmaf(pr, vrow[t + r * 256], acc[r]);
  }
#pragma unroll
  for (int r = 0; r < 4; ++r) part[((size_t)p * BATCH + b) * EMBD + t + r * 256] = acc[r];
}

// ---------------- logits v4 ----------------
// grid (64, 8), 256 threads, __launch_bounds__(256,2). Block: 1024 cols (4/thread,
// stride 256) x 128-i K-chunk staged in LDS. Ratio 16 FMA per ds_read_b128 keeps
// LDS issue below the 1/12-per-cycle capacity at full HBM weight-stream rate.
__global__ __launch_bounds__(256, 2) void logits_v4(const float* __restrict__ X,
                                                    const float* __restrict__ Wl,
                                                    float* __restrict__ part) {
  __shared__ float xt[128][BATCH];  // 16 KB
  int t = threadIdx.x;
  int p = blockIdx.y;
  int q0 = p * 128;
  for (int m = t; m < 128 * BATCH; m += 256) {
    int i = m >> 5, b = m & 31;
    xt[i][b] = X[b * EMBD + q0 + i];
  }
  __syncthreads();

  int jb = blockIdx.x * 1024;
  int j0 = jb + t;
  int j1 = jb + 256 + t;
  int j2 = jb + 512 + t;
  int j3 = jb + 768 + t;
  bool v3 = (j3 < VOC);  // only last block's t=255 is OOB
  float acc0[BATCH], acc1[BATCH], acc2[BATCH], acc3[BATCH];
#pragma unroll
  for (int b = 0; b < BATCH; ++b) { acc0[b] = 0.f; acc1[b] = 0.f; acc2[b] = 0.f; acc3[b] = 0.f; }

  const float* wp = Wl + (size_t)q0 * VOC;
#pragma unroll 4
  for (int i = 0; i < 128; ++i) {
    const float* wr = wp + (size_t)i * VOC;
    float w0 = wr[j0];
    float w1 = wr[j1];
    float w2 = wr[j2];
    float w3 = v3 ? wr[j3] : 0.f;
#pragma unroll
    for (int b4 = 0; b4 < 8; ++b4) {
      float4 xv = *(const float4*)&xt[i][b4 * 4];
      acc0[b4 * 4 + 0] = fmaf(xv.x, w0, acc0[b4 * 4 + 0]);
      acc0[b4 * 4 + 1] = fmaf(xv.y, w0, acc0[b4 * 4 + 1]);
      acc0[b4 * 4 + 2] = fmaf(xv.z, w0, acc0[b4 * 4 + 2]);
      acc0[b4 * 4 + 3] = fmaf(xv.w, w0, acc0[b4 * 4 + 3]);
      acc1[b4 * 4 + 0] = fmaf(xv.x, w1, acc1[b4 * 4 + 0]);
      acc1[b4 * 4 + 1] = fmaf(xv.y, w1, acc1[b4 * 4 + 1]);
      acc1[b4 * 4 + 2] = fmaf(xv.z, w1, acc1[b4 * 4 + 2]);
      acc1[b4 * 4 + 3] = fmaf(xv.w, w1, acc1[b4 * 4 + 3]);
      acc2[b4 * 4 + 0] = fmaf(xv.x, w2, acc2[b4 * 4 + 0]);
      acc2[b4 * 4 + 1] = fmaf(xv.y, w2, acc2[b4 * 4 + 1]);
      acc2[b4 * 4 + 2] = fmaf(xv.z, w2, acc2[b4 * 4 + 2]);
      acc2[b4 * 4 + 3] = fmaf(xv.w, w2, acc2[b4 * 4 + 3]);
      acc3[b4 * 4 + 0] = fmaf(xv.x, w3, acc3[b4 * 4 + 0]);
      acc3[b4 * 4 + 1] = fmaf(xv.y, w3, acc3[b4 * 4 + 1]);
      acc3[b4 * 4 + 2] = fmaf(xv.z, w3, acc3[b4 * 4 + 2]);
      acc3[b4 * 4 + 3] = fmaf(xv.w, w3, acc3[b4 * 4 + 3]);
    }
  }
#pragma unroll
  for (int b = 0; b < BATCH; ++b) {
    float* pr = part + ((size_t)p * BATCH + b) * VOC;
    pr[j0] = acc0[b];
    pr[j1] = acc1[b];
    pr[j2] = acc2[b];
    if (v3) pr[j3] = acc3[b];
  }
}

__global__ void logits_reduce(const float* __restrict__ part, const float* __restrict__ bl,
                              float* __restrict__ out) {
  size_t m = (size_t)blockIdx.x * 256 + threadIdx.x;
  if (m >= (size_t)BATCH * VOC) return;
  int j = (int)(m % VOC);
  float s = 0.f;
#pragma unroll
  for (int p = 0; p < 8; ++p) s += part[(size_t)p * BATCH * VOC + m];
  out[m] = s + bl[j];
}

// fallback (small ws): split batch in halves, full K, direct write
__global__ void logits_splitb(const float* __restrict__ X, const float* __restrict__ Wl,
                              const float* __restrict__ bl, float* __restrict__ out) {
  int j = blockIdx.x * 256 + threadIdx.x;
  if (j >= VOC) return;
  int b0 = blockIdx.y * 16;
  float acc[16];
#pragma unroll
  for (int b = 0; b < 16; ++b) acc[b] = 0.f;
#pragma unroll 8
  for (int i = 0; i < EMBD; ++i) {
    float w = Wl[(size_t)i * VOC + j];
#pragma unroll
    for (int b = 0; b < 16; ++b) acc[b] = fmaf(X[(b0 + b) * EMBD + i], w, acc[b]);
  }
  float bb = bl[j];
#pragma unroll
  for (int b = 0; b < 16; ++b) out[(size_t)(b0 + b) * VOC + j] = acc[b] + bb;
}

extern "C" void kernel_launch(void* const* d_in, const int* in_sizes, int n_in,
                              void* d_out, int out_size, void* d_ws, size_t ws_size,
                              hipStream_t stream) {
  const int* idx = (const int*)d_in[0];
  const float* key_cache = (const float*)d_in[1];
  const float* value_cache = (const float*)d_in[2];
  const float* emb_table = (const float*)d_in[3];
  const float* pos_table = (const float*)d_in[4];
  const float* Wk = (const float*)d_in[5];
  const float* bk = (const float*)d_in[6];
  const float* Wv = (const float*)d_in[7];
  const float* bv = (const float*)d_in[8];
  const float* Wq = (const float*)d_in[9];
  const float* bq = (const float*)d_in[10];
  const float* W1 = (const float*)d_in[11];
  const float* b1 = (const float*)d_in[12];
  const float* W2 = (const float*)d_in[13];
  const float* b2 = (const float*)d_in[14];
  const float* Wl = (const float*)d_in[15];
  const float* bl = (const float*)d_in[16];
  float* out = (float*)d_out;

  float* ws = (float*)d_ws;
  float* x    = ws;                    // 32768
  float* k    = ws + 32768;
  float* v    = ws + 65536;
  float* q    = ws + 98304;
  float* prob = ws + 131072;           // scores -> probs in place
  float* attn = ws + 163840;
  float* h    = ws + 196608;           // 131072
  float* ffn  = ws + 327680;
  float* part = ws + 360448;

  size_t partCap = (ws_size / 4 > 360448) ? ws_size / 4 - 360448 : 0;

  embed_kernel<<<dim3(BATCH), 256, 0, stream>>>(idx, emb_table, pos_table, x);

  // QKV: 32 chunks of 32 (384 blocks) if partials fit, else 8 chunks of 128
  if (partCap >= (size_t)3 * 32 * BATCH * EMBD) {
    qkv_lds<32><<<dim3(4, 32, 3), 256, 0, stream>>>(x, Wk, Wv, Wq, part, 32);
    reduce_qkv<<<dim3(128, 3), 256, 0, stream>>>(part, 32, bk, bv, bq, k, v, q);
  } else {
    qkv_lds<128><<<dim3(4, 8, 3), 256, 0, stream>>>(x, Wk, Wv, Wq, part, 8);
    reduce_qkv<<<dim3(128, 3), 256, 0, stream>>>(part, 8, bk, bv, bq, k, v, q);
  }

  scores_kernel<<<dim3(64, BATCH), 256, 0, stream>>>(q, key_cache, k, prob);
  softmax_kernel<<<dim3(BATCH), 1024, 0, stream>>>(prob);
  pv_kernel<<<dim3(32, BATCH), 256, 0, stream>>>(prob, value_cache, v, part);
  reduce_ep<<<dim3(128), 256, 0, stream>>>(part, 32, nullptr, attn, BATCH * EMBD, 0, 0);

  // FFN1: 16 chunks of 64 (grid 256)
  skgemm_lds<64><<<dim3(16, 16), 256, 0, stream>>>(attn, W1, part, HIDD, EMBD);
  reduce_ep<<<dim3(512), 256, 0, stream>>>(part, 16, b1, h, BATCH * HIDD, HIDD - 1, 1);

  // FFN2: 64 chunks of 64 (grid 256)
  skgemm_lds<64><<<dim3(4, 64), 256, 0, stream>>>(h, W2, part, EMBD, HIDD);
  reduce_ep<<<dim3(128), 256, 0, stream>>>(part, 64, b2, ffn, BATCH * EMBD, EMBD - 1, 0);

  if (partCap >= (size_t)8 * BATCH * VOC) {
    logits_v4<<<dim3(64, 8), 256, 0, stream>>>(ffn, Wl, part);
    logits_reduce<<<dim3(8192), 256, 0, stream>>>(part, bl, out);
  } else {
    logits_splitb<<<dim3(256, 2), 256, 0, stream>>>(ffn, Wl, bl, out);
  }
}

// Round 7
// 245.902 us; speedup vs baseline: 1.0501x; 1.0501x over previous
//
#include <hip/hip_runtime.h>
#include <cstddef>

#define BATCH 32
#define EMBD 1024
#define SCTX 1023   // cached positions
#define CTXF 1024   // full context after concat
#define HIDD 4096
#define VOC 65535

// ---------------- embed: x[b] = emb[idx[b]] + pos[0] ----------------
__global__ void embed_kernel(const int* __restrict__ idx, const float* __restrict__ emb,
                             const float* __restrict__ pos, float* __restrict__ x) {
  int b = blockIdx.x, t = threadIdx.x;  // 32 blocks x 256
  const float4* er = (const float4*)(emb + (size_t)idx[b] * EMBD);
  const float4* pr = (const float4*)pos;
  float4 e = er[t], p = pr[t];
  ((float4*)(x + (size_t)b * EMBD))[t] = make_float4(e.x + p.x, e.y + p.y, e.z + p.z, e.w + p.w);
}

// ---------------- LDS-staged skinny GEMM (X broadcast from LDS) ----------------
template <int CHK>
__global__ __launch_bounds__(256) void skgemm_lds(const float* __restrict__ X,
                                                  const float* __restrict__ W,
                                                  float* __restrict__ Pout, int N, int K) {
  __shared__ float xt[CHK][BATCH];
  int t = threadIdx.x;
  int p = blockIdx.y;
  int i0 = p * CHK;
  for (int m = t; m < CHK * BATCH; m += 256) {
    int i = m >> 5, b = m & 31;
    xt[i][b] = X[b * K + i0 + i];
  }
  __syncthreads();

  int j = blockIdx.x * 256 + t;
  float acc[BATCH];
#pragma unroll
  for (int b = 0; b < BATCH; ++b) acc[b] = 0.f;
  const float* wp = W + (size_t)i0 * N + j;
#pragma unroll 8
  for (int i = 0; i < CHK; ++i) {
    float w = wp[(size_t)i * N];
#pragma unroll
    for (int b = 0; b < BATCH; ++b) acc[b] = fmaf(xt[i][b], w, acc[b]);
  }
#pragma unroll
  for (int b = 0; b < BATCH; ++b) Pout[((size_t)p * BATCH + b) * N + j] = acc[b];
}

// QKV: z selects weight; partial layout [z][p][b][j]
template <int CHK>
__global__ __launch_bounds__(256) void qkv_lds(const float* __restrict__ X,
                                               const float* __restrict__ Wk,
                                               const float* __restrict__ Wv,
                                               const float* __restrict__ Wq,
                                               float* __restrict__ Pout, int nch) {
  __shared__ float xt[CHK][BATCH];
  int t = threadIdx.x;
  int p = blockIdx.y;
  int i0 = p * CHK;
  for (int m = t; m < CHK * BATCH; m += 256) {
    int i = m >> 5, b = m & 31;
    xt[i][b] = X[b * EMBD + i0 + i];
  }
  __syncthreads();

  const float* __restrict__ W = (blockIdx.z == 0) ? Wk : (blockIdx.z == 1) ? Wv : Wq;
  int j = blockIdx.x * 256 + t;
  float acc[BATCH];
#pragma unroll
  for (int b = 0; b < BATCH; ++b) acc[b] = 0.f;
  const float* wp = W + (size_t)i0 * EMBD + j;
#pragma unroll 8
  for (int i = 0; i < CHK; ++i) {
    float w = wp[(size_t)i * EMBD];
#pragma unroll
    for (int b = 0; b < BATCH; ++b) acc[b] = fmaf(xt[i][b], w, acc[b]);
  }
#pragma unroll
  for (int b = 0; b < BATCH; ++b)
    Pout[((size_t)(blockIdx.z * nch + p) * BATCH + b) * EMBD + j] = acc[b];
}

__global__ void reduce_qkv(const float* __restrict__ part, int P,
                           const float* __restrict__ bk, const float* __restrict__ bv,
                           const float* __restrict__ bq,
                           float* __restrict__ kout, float* __restrict__ vout,
                           float* __restrict__ qout) {
  int z = blockIdx.y;
  int m = blockIdx.x * 256 + threadIdx.x;       // < 32768
  float s = 0.f;
  for (int p = 0; p < P; ++p) s += part[(size_t)(z * P + p) * (BATCH * EMBD) + m];
  const float* bias = (z == 0) ? bk : (z == 1) ? bv : bq;
  float* out = (z == 0) ? kout : (z == 1) ? vout : qout;
  out[m] = s + bias[m & (EMBD - 1)];
}

// out[m] = act( sum_p part[p][m] + bias[m & mask] )
__global__ void reduce_ep(const float* __restrict__ part, int P,
                          const float* __restrict__ bias, float* __restrict__ out,
                          int total, int mask, int act) {
  int m = blockIdx.x * 256 + threadIdx.x;
  if (m >= total) return;
  float s = 0.f;
  for (int p = 0; p < P; ++p) s += part[(size_t)p * total + m];
  if (bias) s += bias[m & mask];
  if (act == 1) s = 0.5f * s * (1.f + erff(s * 0.70710678118654752f));
  out[m] = s;
}

// FFN2 reduce: writes ffn[b][j] AND the transposed copy xt_g[j][b] for logits
__global__ void reduce_ffn2(const float* __restrict__ part, int P,
                            const float* __restrict__ bias, float* __restrict__ out,
                            float* __restrict__ out_t) {
  int m = blockIdx.x * 256 + threadIdx.x;       // < 32768
  float s = 0.f;
  for (int p = 0; p < P; ++p) s += part[(size_t)p * (BATCH * EMBD) + m];
  s += bias[m & (EMBD - 1)];
  out[m] = s;
  out_t[(size_t)(m & (EMBD - 1)) * BATCH + (m >> 10)] = s;
}

// ---------------- attention ----------------
// grid (64, 32): block = 4 waves, each wave computes 4 score rows concurrently
__global__ void scores_kernel(const float* __restrict__ q, const float* __restrict__ kcache,
                              const float* __restrict__ knew, float* __restrict__ scores) {
  int b = blockIdx.y;
  int wave = threadIdx.x >> 6, lane = threadIdx.x & 63;
  const float* qb = q + (size_t)b * EMBD;
  float4 qf[4];
#pragma unroll
  for (int r = 0; r < 4; ++r) qf[r] = *(const float4*)(qb + r * 256 + lane * 4);
  int sbase = blockIdx.x * 16 + wave * 4;
  const float* kr[4];
  float acc[4] = {0.f, 0.f, 0.f, 0.f};
#pragma unroll
  for (int it = 0; it < 4; ++it) {
    int s = sbase + it;
    kr[it] = (s < SCTX) ? (kcache + ((size_t)b * SCTX + s) * EMBD)
                        : (knew + (size_t)b * EMBD);
  }
#pragma unroll
  for (int r = 0; r < 4; ++r) {
#pragma unroll
    for (int it = 0; it < 4; ++it) {
      float4 kf = *(const float4*)(kr[it] + r * 256 + lane * 4);
      acc[it] += qf[r].x * kf.x + qf[r].y * kf.y + qf[r].z * kf.z + qf[r].w * kf.w;
    }
  }
#pragma unroll
  for (int it = 0; it < 4; ++it) {
    float a = acc[it];
#pragma unroll
    for (int m = 32; m > 0; m >>= 1) a += __shfl_xor(a, m, 64);
    if (lane == 0) scores[(size_t)b * CTXF + sbase + it] = a * 0.03125f;  // 1/sqrt(1024)
  }
}

__global__ void softmax_kernel(float* __restrict__ sc) {
  int b = blockIdx.x;
  int t = threadIdx.x;  // 1024
  __shared__ float red[16];
  float v = sc[(size_t)b * CTXF + t];
  float m = v;
#pragma unroll
  for (int d = 32; d > 0; d >>= 1) m = fmaxf(m, __shfl_xor(m, d, 64));
  if ((t & 63) == 0) red[t >> 6] = m;
  __syncthreads();
  float bm = red[0];
#pragma unroll
  for (int w = 1; w < 16; ++w) bm = fmaxf(bm, red[w]);
  float e = expf(v - bm);
  __syncthreads();
  float s = e;
#pragma unroll
  for (int d = 32; d > 0; d >>= 1) s += __shfl_xor(s, d, 64);
  if ((t & 63) == 0) red[t >> 6] = s;
  __syncthreads();
  float bs = 0.f;
#pragma unroll
  for (int w = 0; w < 16; ++w) bs += red[w];
  sc[(size_t)b * CTXF + t] = e / bs;
}

// grid (32, 32): 32 chunks of 32 rows
__global__ void pv_kernel(const float* __restrict__ probs, const float* __restrict__ vcache,
                          const float* __restrict__ vnew, float* __restrict__ part) {
  int b = blockIdx.y;
  int p = blockIdx.x;
  int t = threadIdx.x;  // 256
  float acc[4] = {0.f, 0.f, 0.f, 0.f};
  int s0 = p * 32;
#pragma unroll 4
  for (int s = s0; s < s0 + 32; ++s) {
    float pr = probs[(size_t)b * CTXF + s];
    const float* vrow = (s < SCTX) ? (vcache + ((size_t)b * SCTX + s) * EMBD)
                                   : (vnew + (size_t)b * EMBD);
#pragma unroll
    for (int r = 0; r < 4; ++r) acc[r] = fmaf(pr, vrow[t + r * 256], acc[r]);
  }
#pragma unroll
  for (int r = 0; r < 4; ++r) part[((size_t)p * BATCH + b) * EMBD + t + r * 256] = acc[r];
}

// ---------------- logits v5 ----------------
// grid (128, 4), 256 threads. 2 cols/thread; X read TRANSPOSED from global with
// wave-uniform addresses -> compiler emits s_load (SMEM pipe), no LDS, no per-lane
// X traffic. Per i: 2 coalesced weight loads + 8 s_load_dwordx4 + 64 FMA.
__global__ __launch_bounds__(256) void logits_v5(const float* __restrict__ Xt,
                                                 const float* __restrict__ Wl,
                                                 float* __restrict__ part) {
  int t = threadIdx.x;
  int p = blockIdx.y;
  int q0 = p * 256;

  int jb = blockIdx.x * 512;
  int j0 = jb + t;
  int j1 = jb + 256 + t;
  bool v1 = (j1 < VOC);
  float acc0[BATCH], acc1[BATCH];
#pragma unroll
  for (int b = 0; b < BATCH; ++b) { acc0[b] = 0.f; acc1[b] = 0.f; }

  const float* wp = Wl + (size_t)q0 * VOC;
  const float* xp = Xt + (size_t)q0 * BATCH;
#pragma unroll 4
  for (int i = 0; i < 256; ++i) {
    float w0 = wp[(size_t)i * VOC + j0];
    float w1 = v1 ? wp[(size_t)i * VOC + j1] : 0.f;
    const float* xr = xp + i * BATCH;   // wave-uniform address
#pragma unroll
    for (int b4 = 0; b4 < 8; ++b4) {
      float4 xv = *(const float4*)(xr + b4 * 4);
      acc0[b4 * 4 + 0] = fmaf(xv.x, w0, acc0[b4 * 4 + 0]);
      acc0[b4 * 4 + 1] = fmaf(xv.y, w0, acc0[b4 * 4 + 1]);
      acc0[b4 * 4 + 2] = fmaf(xv.z, w0, acc0[b4 * 4 + 2]);
      acc0[b4 * 4 + 3] = fmaf(xv.w, w0, acc0[b4 * 4 + 3]);
      acc1[b4 * 4 + 0] = fmaf(xv.x, w1, acc1[b4 * 4 + 0]);
      acc1[b4 * 4 + 1] = fmaf(xv.y, w1, acc1[b4 * 4 + 1]);
      acc1[b4 * 4 + 2] = fmaf(xv.z, w1, acc1[b4 * 4 + 2]);
      acc1[b4 * 4 + 3] = fmaf(xv.w, w1, acc1[b4 * 4 + 3]);
    }
  }
#pragma unroll
  for (int b = 0; b < BATCH; ++b) {
    float* pr = part + ((size_t)p * BATCH + b) * VOC;
    pr[j0] = acc0[b];
    if (v1) pr[j1] = acc1[b];
  }
}

__global__ void logits_reduce(const float* __restrict__ part, const float* __restrict__ bl,
                              float* __restrict__ out) {
  size_t m = (size_t)blockIdx.x * 256 + threadIdx.x;
  if (m >= (size_t)BATCH * VOC) return;
  int j = (int)(m % VOC);
  float s = 0.f;
#pragma unroll
  for (int p = 0; p < 4; ++p) s += part[(size_t)p * BATCH * VOC + m];
  out[m] = s + bl[j];
}

// fallback (small ws): split batch in halves, full K, direct write
__global__ void logits_splitb(const float* __restrict__ X, const float* __restrict__ Wl,
                              const float* __restrict__ bl, float* __restrict__ out) {
  int j = blockIdx.x * 256 + threadIdx.x;
  if (j >= VOC) return;
  int b0 = blockIdx.y * 16;
  float acc[16];
#pragma unroll
  for (int b = 0; b < 16; ++b) acc[b] = 0.f;
#pragma unroll 8
  for (int i = 0; i < EMBD; ++i) {
    float w = Wl[(size_t)i * VOC + j];
#pragma unroll
    for (int b = 0; b < 16; ++b) acc[b] = fmaf(X[(b0 + b) * EMBD + i], w, acc[b]);
  }
  float bb = bl[j];
#pragma unroll
  for (int b = 0; b < 16; ++b) out[(size_t)(b0 + b) * VOC + j] = acc[b] + bb;
}

extern "C" void kernel_launch(void* const* d_in, const int* in_sizes, int n_in,
                              void* d_out, int out_size, void* d_ws, size_t ws_size,
                              hipStream_t stream) {
  const int* idx = (const int*)d_in[0];
  const float* key_cache = (const float*)d_in[1];
  const float* value_cache = (const float*)d_in[2];
  const float* emb_table = (const float*)d_in[3];
  const float* pos_table = (const float*)d_in[4];
  const float* Wk = (const float*)d_in[5];
  const float* bk = (const float*)d_in[6];
  const float* Wv = (const float*)d_in[7];
  const float* bv = (const float*)d_in[8];
  const float* Wq = (const float*)d_in[9];
  const float* bq = (const float*)d_in[10];
  const float* W1 = (const float*)d_in[11];
  const float* b1 = (const float*)d_in[12];
  const float* W2 = (const float*)d_in[13];
  const float* b2 = (const float*)d_in[14];
  const float* Wl = (const float*)d_in[15];
  const float* bl = (const float*)d_in[16];
  float* out = (float*)d_out;

  float* ws = (float*)d_ws;
  float* x    = ws;                    // 32768
  float* k    = ws + 32768;
  float* v    = ws + 65536;
  float* q    = ws + 98304;
  float* prob = ws + 131072;           // scores -> probs in place
  float* attn = ws + 163840;
  float* h    = ws + 196608;           // 131072
  float* ffn  = ws + 327680;           // 32768
  float* xt_g = ws + 360448;           // 32768 (ffn transposed [j][b])
  float* part = ws + 393216;

  size_t partCap = (ws_size / 4 > 393216) ? ws_size / 4 - 393216 : 0;

  embed_kernel<<<dim3(BATCH), 256, 0, stream>>>(idx, emb_table, pos_table, x);

  // QKV: 32 chunks of 32 (384 blocks) if partials fit, else 8 chunks of 128
  if (partCap >= (size_t)3 * 32 * BATCH * EMBD) {
    qkv_lds<32><<<dim3(4, 32, 3), 256, 0, stream>>>(x, Wk, Wv, Wq, part, 32);
    reduce_qkv<<<dim3(128, 3), 256, 0, stream>>>(part, 32, bk, bv, bq, k, v, q);
  } else {
    qkv_lds<128><<<dim3(4, 8, 3), 256, 0, stream>>>(x, Wk, Wv, Wq, part, 8);
    reduce_qkv<<<dim3(128, 3), 256, 0, stream>>>(part, 8, bk, bv, bq, k, v, q);
  }

  scores_kernel<<<dim3(64, BATCH), 256, 0, stream>>>(q, key_cache, k, prob);
  softmax_kernel<<<dim3(BATCH), 1024, 0, stream>>>(prob);
  pv_kernel<<<dim3(32, BATCH), 256, 0, stream>>>(prob, value_cache, v, part);
  reduce_ep<<<dim3(128), 256, 0, stream>>>(part, 32, nullptr, attn, BATCH * EMBD, 0, 0);

  // FFN1: 16 chunks of 64 (grid 256)
  skgemm_lds<64><<<dim3(16, 16), 256, 0, stream>>>(attn, W1, part, HIDD, EMBD);
  reduce_ep<<<dim3(512), 256, 0, stream>>>(part, 16, b1, h, BATCH * HIDD, HIDD - 1, 1);

  // FFN2: 64 chunks of 64 (grid 256); reduce also emits transposed copy for logits
  skgemm_lds<64><<<dim3(4, 64), 256, 0, stream>>>(h, W2, part, EMBD, HIDD);
  reduce_ffn2<<<dim3(128), 256, 0, stream>>>(part, 64, b2, ffn, xt_g);

  if (partCap >= (size_t)4 * BATCH * VOC) {
    logits_v5<<<dim3(128, 4), 256, 0, stream>>>(xt_g, Wl, part);
    logits_reduce<<<dim3(8192), 256, 0, stream>>>(part, bl, out);
  } else {
    logits_splitb<<<dim3(256, 2), 256, 0, stream>>>(ffn, Wl, bl, out);
  }
}